// Round 5
// baseline (176.286 us; speedup 1.0000x reference)
//
#include <hip/hip_runtime.h>

// LIF scan: z [B=32, T=1024, H=512] fp32 -> out [32,1024,512] fp32
//   V_t = 0.9*V_{t-1} + z[:,t-1,:] - (V_{t-1} > 1)      (exact fp32 op order)
//   out[:,t,:] = (V_t > 1) ? 1 : 0,  out[:,0,:] = 0
//
// R1-R4 lesson: at 1 wave/CU (16384 chains) the compiler sustains only ~10
// VMEM loads in flight per wave (register pipelines get dissolved; volatile
// serializes; LDS-DMA hits conservative vmcnt(0) + store-vmcnt pollution).
// In-flight bytes = waves x ~10 x 256 B, so the only structural lever is MORE
// WAVES. This kernel splits T into 8 segments of 128 steps computed in
// parallel (2048 waves = 8 waves/CU). Each segment warms up from V=0 over the
// W=512 steps preceding it: the map contracts by 0.9/step and the subtract-
// reset re-syncs threshold straddles, so the speculative trajectory becomes
// BIT-EXACT before the segment's first output. Segments 0..4's warmup reaches
// s=0 (V=0 true -> exact by construction); only g=5,6,7 are speculative, with
// ~320 steps of post-cascade margin (per-chain failure ~1e-11).
// Warmup re-reads (~3.8x) are served by the 256 MiB L3 (z = 64 MiB resident);
// HBM traffic stays ~100 MB -> BW-bound target ~20 us.

#define LIF_H 512
#define SEG   128     // output steps per segment
#define WARM  512     // speculative burn-in steps

__global__ __launch_bounds__(256, 2) void lif_kernel(const float* __restrict__ z,
                                                     float* __restrict__ out) {
    const int beta = blockIdx.x;            // 0..511
    const int half = beta & 1;              // h 0..255 / 256..511
    const int g    = (beta >> 1) & 7;       // time segment
    const int b    = beta >> 4;             // batch row
    const int h    = (half << 8) + threadIdx.x;
    const size_t base = (size_t)b * (1024 * LIF_H) + h;

    const float* zp = z + base;             // z[b, s, h]    = zp[s*512]
    float* op = out + base;                 // out[b, t, h]  = op[t*512]

    const int s_begin = g * SEG;                       // first stored step
    const int s_end   = (g == 7) ? 1023 : s_begin + SEG;
    int s0 = s_begin - WARM;                           // warmup start
    if (s0 < 0) s0 = 0;                                // g<=4: exact from s=0

    float V = 0.0f;

    // ---- burn-in: converge V to the true trajectory (no stores) ----
#pragma unroll 8
    for (int s = s0; s < s_begin; ++s) {
        const float zv = zp[(size_t)s * LIF_H];
        const float v0 = __fadd_rn(__fmul_rn(0.9f, V), zv);
        V = (V > 1.0f) ? __fsub_rn(v0, 1.0f) : v0;
    }

    if (g == 0) op[0] = 0.0f;               // t = 0 row stays zero

    // ---- owned segment: exact reference op order, spike stores ----
#pragma unroll 4
    for (int s = s_begin; s < s_end; ++s) {
        const float zv = zp[(size_t)s * LIF_H];
        const float v0 = __fadd_rn(__fmul_rn(0.9f, V), zv);
        const float Vn = (V > 1.0f) ? __fsub_rn(v0, 1.0f) : v0;
        op[(size_t)(s + 1) * LIF_H] = (Vn > 1.0f) ? 1.0f : 0.0f;
        V = Vn;
    }
}

extern "C" void kernel_launch(void* const* d_in, const int* in_sizes, int n_in,
                              void* d_out, int out_size, void* d_ws, size_t ws_size,
                              hipStream_t stream) {
    const float* z = (const float*)d_in[0];
    float* out = (float*)d_out;
    dim3 block(256);
    dim3 grid(512);                         // 32 b x 8 segments x 2 h-halves
    hipLaunchKernelGGL(lif_kernel, grid, block, 0, stream, z, out);
}

// Round 6
// 165.716 us; speedup vs baseline: 1.0638x; 1.0638x over previous
//
#include <hip/hip_runtime.h>

// LIF scan: z [B=32, T=1024, H=512] fp32 -> out [32,1024,512] fp32
//   V_t = 0.9*V_{t-1} + z[:,t-1,:] - (V_{t-1} > 1)      (exact fp32 op order)
//   out[:,t,:] = (V_t > 1) ? 1 : 0,  out[:,0,:] = 0
//
// Structure (validated R5, absmax 0.0): T split into 8 segments of 128 steps
// computed in parallel; each warms up from V=0 over the <=512 steps before
// its window (0.9-contraction + corrective subtract-reset kicks make the
// speculative trajectory bit-exact well before the first stored output;
// g<=4 reach s=0 and are exact by construction). 2048 waves = 8 waves/CU.
//
// R5 lesson: runtime trip counts killed #pragma unroll (VGPR=8, 1 load in
// flight, 360 cyc/step). Fix: template-specialized segments with COMPILE-TIME
// trip counts, dispatched on block-uniform blockIdx.y. R1 showed the compiler
// sustains ~10 loads in flight per wave in constant-trip unrolled loops;
// x 2048 waves = ~5 MB in flight > 2.4 MB HBM BDP -> bandwidth-bound.

#define LIF_H 512

template <int WN, int SN>
__device__ __forceinline__ void run_seg(const float* __restrict__ zp,
                                        float* __restrict__ op,
                                        const int s_begin) {
    float V = 0.0f;

    // ---- burn-in: WN steps ending at s_begin (no stores) ----
    if (WN > 0) {
        const float* zw = zp + (size_t)(s_begin - WN) * LIF_H;
#pragma unroll 8
        for (int i = 0; i < WN; ++i) {
            const float zv = zw[(size_t)i * LIF_H];
            const float v0 = __fadd_rn(__fmul_rn(0.9f, V), zv);
            V = (V > 1.0f) ? __fsub_rn(v0, 1.0f) : v0;
        }
    }

    // ---- owned segment: SN steps, spike stores ----
    const float* zs = zp + (size_t)s_begin * LIF_H;
    float* os = op + (size_t)(s_begin + 1) * LIF_H;
#pragma unroll 8
    for (int i = 0; i < SN; ++i) {
        const float zv = zs[(size_t)i * LIF_H];
        const float v0 = __fadd_rn(__fmul_rn(0.9f, V), zv);
        const float Vn = (V > 1.0f) ? __fsub_rn(v0, 1.0f) : v0;
        os[(size_t)i * LIF_H] = (Vn > 1.0f) ? 1.0f : 0.0f;
        V = Vn;
    }
}

__global__ __launch_bounds__(256, 2) void lif_kernel(const float* __restrict__ z,
                                                     float* __restrict__ out) {
    const int g = blockIdx.y;                       // time segment, block-uniform
    const int b = blockIdx.x >> 1;                  // batch row
    const int h = ((blockIdx.x & 1) << 8) + threadIdx.x;
    const size_t base = (size_t)b * (1024 * LIF_H) + h;

    const float* zp = z + base;                     // z[b, s, h]   = zp[s*512]
    float* op = out + base;                         // out[b, t, h] = op[t*512]

    if (g == 0) {
        op[0] = 0.0f;                               // t = 0 row stays zero
        run_seg<0, 128>(zp, op, 0);
    } else if (g == 1) {
        run_seg<128, 128>(zp, op, 128);
    } else if (g == 2) {
        run_seg<256, 128>(zp, op, 256);
    } else if (g == 3) {
        run_seg<384, 128>(zp, op, 384);
    } else if (g == 4) {
        run_seg<512, 128>(zp, op, 512);
    } else if (g == 5) {
        run_seg<512, 128>(zp, op, 640);
    } else if (g == 6) {
        run_seg<512, 128>(zp, op, 768);
    } else {
        run_seg<512, 127>(zp, op, 896);             // outputs t = 897..1023
    }
}

extern "C" void kernel_launch(void* const* d_in, const int* in_sizes, int n_in,
                              void* d_out, int out_size, void* d_ws, size_t ws_size,
                              hipStream_t stream) {
    const float* z = (const float*)d_in[0];
    float* out = (float*)d_out;
    dim3 block(256);
    dim3 grid(64, 8);                               // 32 b x 2 h-halves, 8 segments
    hipLaunchKernelGGL(lif_kernel, grid, block, 0, stream, z, out);
}

// Round 7
// 132.848 us; speedup vs baseline: 1.3270x; 1.2474x over previous
//
#include <hip/hip_runtime.h>

// LIF scan: z [B=32, T=1024, H=512] fp32 -> out [32,1024,512] fp32
//   V_t = 0.9*V_{t-1} + z[:,t-1,:] - (V_{t-1} > 1)      (exact fp32 op order)
//   out[:,t,:] = (V_t > 1) ? 1 : 0,  out[:,0,:] = 0
//
// R1/R3/R6 lesson: with a register-chain consumer, the scheduler emits
// load->wait->use->load... (in-order issue => 1 load in flight/wave) and no
// pragma/template/sched_barrier variant breaks this. R4 lesson: global->LDS
// DMA triggers conservative vmcnt(0) before every ds_read (DMA can alias the
// read buffer) => serialized. This kernel stages through LDS with PLAIN
// register loads + ds_write: program order is [32 independent loads] ->
// s_waitcnt -> [32 ds_writes], so the wait structurally sits AFTER the whole
// batch — 32 loads in flight per wave no matter how the scheduler shuffles.
// Reg-loads can't alias LDS, so ds_reads need no vmcnt. Exact scan (no
// speculation): 256 blocks x 64 threads = 1 wave/CU; tile = 32 steps x 64 h
// (8 KiB), double-buffered. 256 waves x 32 x 256 B ~= 2 MB in flight ~= BDP.
// Single-wave block => no __syncthreads needed (lgkmcnt orders LDS in-wave).

#define LIF_H 512
#define TS 32            // time steps per tile; 32 tiles cover s = 0..1023

__global__ __launch_bounds__(64, 1) void lif_kernel(const float* __restrict__ z,
                                                    float* __restrict__ out) {
    __shared__ float Abuf[TS * 64];
    __shared__ float Bbuf[TS * 64];

    const int t = threadIdx.x;                  // 0..63
    const int blk = blockIdx.x;                 // 0..255
    const int b = blk >> 3;                     // 8 blocks per batch row
    const int h0 = (blk & 7) << 6;              // 64 h-chains per block
    const size_t base = (size_t)b * (1024 * LIF_H) + h0 + t;

    const float* zp = z + base;                 // z[b, s, h0+t]   = zp[s*512]
    float* op = out + base;                     // out[b, q, h0+t] = op[q*512]

    op[0] = 0.0f;                               // t = 0 row stays zero

    float r[TS];

    // ---- stage tile 0 -> A ----
#pragma unroll
    for (int j = 0; j < TS; ++j) r[j] = zp[(size_t)j * LIF_H];
#pragma unroll
    for (int j = 0; j < TS; ++j) Abuf[j * 64 + t] = r[j];

    float V = 0.0f;

    // tiles 0..30: compute 32 steps from cur, prefetch tile k+1 into nxt
    for (int k = 0; k < 31; ++k) {
        const float* cur = (k & 1) ? Bbuf : Abuf;
        float* nxt = (k & 1) ? Abuf : Bbuf;

        // prefetch tile k+1 (32 independent coalesced loads)
#pragma unroll
        for (int j = 0; j < TS; ++j)
            r[j] = zp[(size_t)((k + 1) * TS + j) * LIF_H];

        // compute tile k (exact reference op order, no FMA contraction)
#pragma unroll
        for (int i = 0; i < TS; ++i) {
            const float zv = cur[i * 64 + t];
            const float v0 = __fadd_rn(__fmul_rn(0.9f, V), zv);
            const float Vn = (V > 1.0f) ? __fsub_rn(v0, 1.0f) : v0;
            op[(size_t)(k * TS + i + 1) * LIF_H] = (Vn > 1.0f) ? 1.0f : 0.0f;
            V = Vn;
        }

        // commit prefetch to the other buffer (waits the whole load batch)
#pragma unroll
        for (int j = 0; j < TS; ++j) nxt[j * 64 + t] = r[j];
    }

    // tail: tile 31 (parity -> B), steps s = 992..1022 (31 steps)
#pragma unroll
    for (int i = 0; i < TS - 1; ++i) {
        const float zv = Bbuf[i * 64 + t];
        const float v0 = __fadd_rn(__fmul_rn(0.9f, V), zv);
        const float Vn = (V > 1.0f) ? __fsub_rn(v0, 1.0f) : v0;
        op[(size_t)(31 * TS + i + 1) * LIF_H] = (Vn > 1.0f) ? 1.0f : 0.0f;
        V = Vn;
    }
}

extern "C" void kernel_launch(void* const* d_in, const int* in_sizes, int n_in,
                              void* d_out, int out_size, void* d_ws, size_t ws_size,
                              hipStream_t stream) {
    const float* z = (const float*)d_in[0];
    float* out = (float*)d_out;
    dim3 block(64);
    dim3 grid(256);                             // 32 b x 8 h-slices, 1 wave/CU
    hipLaunchKernelGGL(lif_kernel, grid, block, 0, stream, z, out);
}

// Round 8
// 120.760 us; speedup vs baseline: 1.4598x; 1.1001x over previous
//
#include <hip/hip_runtime.h>

// LIF scan: z [B=32, T=1024, H=512] fp32 -> out [32,1024,512] fp32
//   V_t = 0.9*V_{t-1} + z[:,t-1,:] - (V_{t-1} > 1)      (exact fp32 op order)
//   out[:,t,:] = (V_t > 1) ? 1 : 0,  out[:,0,:] = 0
//
// Session lessons:
//   R1/R3/R6: loads consumed by the serial V-chain get sunk to their uses
//     (1 load in flight/wave). R2: volatile => vmcnt(0) each. R4: LDS-DMA =>
//     conservative vmcnt(0) before ds_reads. R7: LDS-commit launders the
//     GLOBAL batch (VGPR=68 proved it) but per-step ds_reads then serialize
//     at ~120 cyc LDS latency (124 cyc/step measured).
// Fix: launder the load batch with an empty `asm volatile` carrying "+v"
// data deps on all 32 values — loads must all precede it (one batched vmcnt
// wait), and the chain then consumes plain VGPRs with zero load latency.
// No LDS at all. Depth-2 pipeline over three 32-step register tiles:
// at tile m: issue loads m+2, compute m, launder m+1. Loads stay in flight
// ~2 iterations (~2000 cyc >> 900 cyc HBM latency); steady-state in-flight
// = 64 x 256 B x 256 waves ~ 4 MB > 2.4 MB HBM BDP -> bandwidth-bound.

#define LIF_H 512
#define TS 32            // steps per tile; 32 tiles cover s = 0..1023

__device__ __forceinline__ void load32(float (&r)[TS], const float* zp, int tile) {
    const float* s = zp + (size_t)tile * TS * LIF_H;
#pragma unroll
    for (int j = 0; j < TS; ++j) r[j] = s[(size_t)j * LIF_H];
}

// Batch-consume: every load feeding r[] must complete before this point
// (data dep into the asm); afterwards values are plain register operands.
__device__ __forceinline__ void launder32(float (&r)[TS]) {
    asm volatile("" : "+v"(r[0]), "+v"(r[1]), "+v"(r[2]), "+v"(r[3]),
                      "+v"(r[4]), "+v"(r[5]), "+v"(r[6]), "+v"(r[7]),
                      "+v"(r[8]), "+v"(r[9]), "+v"(r[10]), "+v"(r[11]),
                      "+v"(r[12]), "+v"(r[13]), "+v"(r[14]), "+v"(r[15]));
    asm volatile("" : "+v"(r[16]), "+v"(r[17]), "+v"(r[18]), "+v"(r[19]),
                      "+v"(r[20]), "+v"(r[21]), "+v"(r[22]), "+v"(r[23]),
                      "+v"(r[24]), "+v"(r[25]), "+v"(r[26]), "+v"(r[27]),
                      "+v"(r[28]), "+v"(r[29]), "+v"(r[30]), "+v"(r[31]));
}

template <int SN>
__device__ __forceinline__ float compute_tile(const float (&r)[TS], int tile,
                                              float V, float* __restrict__ op) {
    float* o = op + (size_t)(tile * TS + 1) * LIF_H;
#pragma unroll
    for (int i = 0; i < SN; ++i) {
        const float v0 = __fadd_rn(__fmul_rn(0.9f, V), r[i]);
        const float Vn = (V > 1.0f) ? __fsub_rn(v0, 1.0f) : v0;
        o[(size_t)i * LIF_H] = (Vn > 1.0f) ? 1.0f : 0.0f;
        V = Vn;
    }
    return V;
}

__global__ __launch_bounds__(64, 1) void lif_kernel(const float* __restrict__ z,
                                                    float* __restrict__ out) {
    const int t = threadIdx.x;                  // 0..63
    const int blk = blockIdx.x;                 // 0..255
    const int b = blk >> 3;                     // 8 blocks per batch row
    const int h0 = (blk & 7) << 6;              // 64 h-chains per block
    const size_t base = (size_t)b * (1024 * LIF_H) + h0 + t;

    const float* zp = z + base;                 // z[b, s, h0+t]   = zp[s*512]
    float* op = out + base;                     // out[b, q, h0+t] = op[q*512]

    op[0] = 0.0f;                               // t = 0 row stays zero

    float rA[TS], rB[TS], rC[TS];

    // prologue: tiles 0,1 in flight; launder 0 (waits tile0 only: vmcnt<=32)
    load32(rA, zp, 0);
    load32(rB, zp, 1);
    launder32(rA);

    float V = 0.0f;

    // main: tiles 0..29, rotation unrolled x3 (tiles m, m+1, m+2)
    for (int m = 0; m < 30; m += 3) {
        load32(rC, zp, m + 2);
        V = compute_tile<TS>(rA, m, V, op);
        launder32(rB);                           // tile m+1 landed ~1 iter ago

        load32(rA, zp, m + 3);
        V = compute_tile<TS>(rB, m + 1, V, op);
        launder32(rC);

        load32(rB, zp, m + 4);                   // m=27 -> tile 31 (s<=1023, in-bounds)
        V = compute_tile<TS>(rC, m + 2, V, op);
        launder32(rA);
    }

    // epilogue: tile 30 (rA, laundered), tile 31 (rB; 31 steps -> t<=1023)
    V = compute_tile<TS>(rA, 30, V, op);
    launder32(rB);
    compute_tile<TS - 1>(rB, 31, V, op);
}

extern "C" void kernel_launch(void* const* d_in, const int* in_sizes, int n_in,
                              void* d_out, int out_size, void* d_ws, size_t ws_size,
                              hipStream_t stream) {
    const float* z = (const float*)d_in[0];
    float* out = (float*)d_out;
    dim3 block(64);
    dim3 grid(256);                             // 32 b x 8 h-slices, 1 wave/CU
    hipLaunchKernelGGL(lif_kernel, grid, block, 0, stream, z, out);
}